// Round 14
// baseline (317.269 us; speedup 1.0000x reference)
//
#include <hip/hip_runtime.h>
#include <cstdint>
#include <cstddef>

// ---------------------------------------------------------------------------
// GCN 4-layer + residual + FC on MI355X, round 14.
// - bucket_kernel: no LDS edge staging (global re-read, L2-hot), 4KB LDS,
//   ACHUNK 2048 -> 782 blocks (grid was the occupancy limiter).
// - Everything else: round-13 exact (298us config).
// ---------------------------------------------------------------------------

#define SLOTS 64
#define BCAP 5120
#define ACHUNK 2048

typedef __attribute__((ext_vector_type(8))) short bf16x8;
typedef __attribute__((ext_vector_type(4))) float f32x4;

__device__ __forceinline__ unsigned short f2bf(float f) {
  union { float f; unsigned u; } v; v.f = f;
  unsigned r = (v.u + 0x7fffu + ((v.u >> 16) & 1u)) >> 16;
  return (unsigned short)r;
}
__device__ __forceinline__ void bf2x2(unsigned u, float* lo, float* hi) {
  union { unsigned x; float f; } a, b;
  a.x = u << 16; b.x = u & 0xFFFF0000u;
  *lo = a.f; *hi = b.f;
}
__device__ __forceinline__ bf16x8 cvt8(float4 f0, float4 f1) {
  bf16x8 v;
  v[0] = (short)f2bf(f0.x); v[1] = (short)f2bf(f0.y);
  v[2] = (short)f2bf(f0.z); v[3] = (short)f2bf(f0.w);
  v[4] = (short)f2bf(f1.x); v[5] = (short)f2bf(f1.y);
  v[6] = (short)f2bf(f1.z); v[7] = (short)f2bf(f1.w);
  return v;
}

#define UNPACK_ADD(u, A)                         \
  { float f0_, f1_, f2_, f3_;                    \
    bf2x2((u).x, &f0_, &f1_);                    \
    bf2x2((u).y, &f2_, &f3_);                    \
    A[0] += f0_; A[1] += f1_; A[2] += f2_; A[3] += f3_; }

// ---------------------------------------------------------------------------
// prep: zero bucket cursors + build bf16 W^T for all weight matrices.
// ---------------------------------------------------------------------------
__global__ void prep_kernel(const float* __restrict__ W1, const float* __restrict__ W2,
                            const float* __restrict__ W3, const float* __restrict__ W4,
                            const float* __restrict__ Wres,
                            unsigned short* __restrict__ WT,
                            int* __restrict__ gcur_d, int* __restrict__ gcur_s, int nbuck) {
  int i = blockIdx.x * blockDim.x + threadIdx.x;
  if (i < nbuck) { gcur_d[i] = 0; gcur_s[i] = 0; }
  if (i < 8192) {
    int c = i >> 7, k = i & 127;
    WT[i] = f2bf(W1[k * 64 + c]);
  } else if (i < 12288) {
    int j = i - 8192; int c = j >> 6, k = j & 63;
    WT[i] = f2bf(W2[k * 64 + c]);
  } else if (i < 16384) {
    int j = i - 12288; int c = j >> 6, k = j & 63;
    WT[i] = f2bf(W3[k * 64 + c]);
  } else if (i < 20480) {
    int j = i - 16384; int c = j >> 6, k = j & 63;
    WT[i] = f2bf(W4[k * 64 + c]);
  } else if (i < 28672) {
    int j = i - 20480; int c = j >> 7, k = j & 127;
    WT[i] = f2bf(Wres[k * 64 + c]);
  }
}

// ---------------------------------------------------------------------------
// Pass A: bucket edges by dst>>8 (payload dl<<24|src) and src>>8 (byte).
// No LDS edge staging: edges are read twice from global (2nd pass L2-hot).
// LDS = 2x512 histogram bins only -> occupancy no longer LDS/grid-limited.
// ---------------------------------------------------------------------------
__global__ __launch_bounds__(256) void bucket_kernel(
    const int* __restrict__ src, const int* __restrict__ dst,
    int* __restrict__ gcur_d, int* __restrict__ gcur_s,
    unsigned* __restrict__ dbuck, unsigned char* __restrict__ sbuck,
    int E, int nbuck) {
  __shared__ int run_d[512];
  __shared__ int run_s[512];
  const int t = threadIdx.x;
  const int base = blockIdx.x * ACHUNK;
  int cnt = E - base;
  if (cnt > ACHUNK) cnt = ACHUNK;

  for (int i = t; i < 512; i += 256) { run_d[i] = 0; run_s[i] = 0; }
  __syncthreads();
  for (int i = t; i < cnt; i += 256) {
    atomicAdd(&run_d[dst[base + i] >> 8], 1);
    atomicAdd(&run_s[src[base + i] >> 8], 1);
  }
  __syncthreads();
  // Reserve global runs. UNIFORM trip count so barriers are non-divergent.
  {
    const int iters = (nbuck + 255) >> 8;
    for (int it = 0; it < iters; ++it) {
      int i = it * 256 + t;
      int hd = 0, hs = 0;
      if (i < nbuck) { hd = run_d[i]; hs = run_s[i]; }
      __syncthreads();
      if (i < nbuck) {
        run_d[i] = hd ? atomicAdd(&gcur_d[i], hd) : 0;
        run_s[i] = hs ? atomicAdd(&gcur_s[i], hs) : 0;
      }
      __syncthreads();
    }
  }
  for (int i = t; i < cnt; i += 256) {
    int d = dst[base + i], s = src[base + i];
    int bd = d >> 8;
    int pd = atomicAdd(&run_d[bd], 1);
    if (pd < BCAP) dbuck[(size_t)bd * BCAP + pd] = ((unsigned)(d & 255) << 24) | (unsigned)s;
    int bs = s >> 8;
    int ps = atomicAdd(&run_s[bs], 1);
    if (ps < BCAP) sbuck[(size_t)bs * BCAP + ps] = (unsigned char)(s & 255);
  }
}

// ---------------------------------------------------------------------------
// Pass B (merged): per 256-node bucket -- dst scatter to col slots + cnt +
// dnorm, AND src histogram -> snorm.
// ---------------------------------------------------------------------------
__global__ __launch_bounds__(256) void csrdeg_kernel(
    const unsigned* __restrict__ dbuck, const int* __restrict__ gcur_d,
    const unsigned char* __restrict__ sbuck, const int* __restrict__ gcur_s,
    int* __restrict__ col, int* __restrict__ cnt_arr,
    float* __restrict__ dnorm, float* __restrict__ snorm, int N) {
  __shared__ int cur[256];
  __shared__ int curs[256];
  const int b = blockIdx.x;
  const int t = threadIdx.x;
  const int node0 = b << 8;
  cur[t] = 0;
  curs[t] = 0;
  __syncthreads();
  int cntd = gcur_d[b];
  if (cntd > BCAP) cntd = BCAP;
  const unsigned* p = dbuck + (size_t)b * BCAP;
  for (int i = t; i < cntd; i += 256) {
    unsigned e = p[i];
    int nl = e >> 24;
    int s = (int)(e & 0x00FFFFFFu);
    int pos = atomicAdd(&cur[nl], 1);
    if (pos < SLOTS) col[(size_t)(node0 + nl) * SLOTS + pos] = s;
  }
  int cnts = gcur_s[b];
  if (cnts > BCAP) cnts = BCAP;
  const unsigned char* ps = sbuck + (size_t)b * BCAP;
  for (int i = t; i < cnts; i += 256) atomicAdd(&curs[ps[i]], 1);
  __syncthreads();
  int node = node0 + t;
  if (node < N) {
    int c = cur[t];
    cnt_arr[node] = c;
    dnorm[node] = rsqrtf((float)(c < 1 ? 1 : c));
    int cs = curs[t];
    snorm[node] = rsqrtf((float)(cs < 1 ? 1 : cs));
  }
}

// ---------------------------------------------------------------------------
// MFMA GEMM layer 1 + residual: B-fragments fully hoisted to registers
// (static indices), 128 nodes per block (2 tiles), LDS epilogue.
// ---------------------------------------------------------------------------
__global__ __launch_bounds__(256, 2) void gemm1_mfma_kernel(
    const float* __restrict__ X, const unsigned short* __restrict__ W1T,
    const unsigned short* __restrict__ WresT, const float* __restrict__ bres,
    const float* __restrict__ norm,
    unsigned short* __restrict__ Hout, unsigned short* __restrict__ Rout, int n) {
  __shared__ float ol[64][68];
  const int t = threadIdx.x;
  const int l = t & 63;
  const int w = t >> 6;
  const int base0 = blockIdx.x * 128;
  const int cc16 = l & 15, kg = l >> 4;

  bf16x8 b1[4][4], br[4][4];
#pragma unroll
  for (int kh = 0; kh < 4; kh++) {
#pragma unroll
    for (int ct = 0; ct < 4; ct++) {
      b1[kh][ct] = *(const bf16x8*)(W1T + (size_t)(ct * 16 + cc16) * 128 + kh * 32 + kg * 8);
      br[kh][ct] = *(const bf16x8*)(WresT + (size_t)(ct * 16 + cc16) * 128 + kh * 32 + kg * 8);
    }
  }

  for (int q = 0; q < 2; q++) {
    const int node0 = base0 + q * 64;
    if (node0 >= n) break;

    int arow = node0 + w * 16 + cc16;
    if (arow > n - 1) arow = n - 1;
    const float* ap = X + (size_t)arow * 128 + kg * 8;
    bf16x8 a[4];
#pragma unroll
    for (int kh = 0; kh < 4; kh++) {
      float4 f0 = *(const float4*)(ap + kh * 32);
      float4 f1 = *(const float4*)(ap + kh * 32 + 4);
      a[kh] = cvt8(f0, f1);
    }

    f32x4 acc[4], acc2[4];
#pragma unroll
    for (int ct = 0; ct < 4; ct++) {
      acc[ct] = (f32x4){0.f, 0.f, 0.f, 0.f};
      acc2[ct] = (f32x4){0.f, 0.f, 0.f, 0.f};
    }
#pragma unroll
    for (int kh = 0; kh < 4; kh++) {
#pragma unroll
      for (int ct = 0; ct < 4; ct++) {
        acc[ct] = __builtin_amdgcn_mfma_f32_16x16x32_bf16(a[kh], b1[kh][ct], acc[ct], 0, 0, 0);
        acc2[ct] = __builtin_amdgcn_mfma_f32_16x16x32_bf16(a[kh], br[kh][ct], acc2[ct], 0, 0, 0);
      }
    }

    // H epilogue
#pragma unroll
    for (int ct = 0; ct < 4; ct++)
#pragma unroll
      for (int i = 0; i < 4; i++)
        ol[w * 16 + kg * 4 + i][ct * 16 + cc16] = acc[ct][i];
    __syncthreads();
    {
      int r2 = t >> 2, cg = (t & 3) * 16;
      int node = node0 + r2;
      if (node < n) {
        float s = norm[node];
        unsigned short o[16];
#pragma unroll
        for (int i = 0; i < 16; i++) o[i] = f2bf(ol[r2][cg + i] * s);
        *(uint4*)&Hout[(size_t)node * 64 + cg] = *(const uint4*)&o[0];
        *(uint4*)&Hout[(size_t)node * 64 + cg + 8] = *(const uint4*)&o[8];
      }
    }
    __syncthreads();

    // R epilogue
#pragma unroll
    for (int ct = 0; ct < 4; ct++)
#pragma unroll
      for (int i = 0; i < 4; i++)
        ol[w * 16 + kg * 4 + i][ct * 16 + cc16] = acc2[ct][i];
    __syncthreads();
    {
      int r2 = t >> 2, cg = (t & 3) * 16;
      int node = node0 + r2;
      if (node < n) {
        unsigned short o[16];
#pragma unroll
        for (int i = 0; i < 16; i++) o[i] = f2bf(ol[r2][cg + i] + bres[cg + i]);
        *(uint4*)&Rout[(size_t)node * 64 + cg] = *(const uint4*)&o[0];
        *(uint4*)&Rout[(size_t)node * 64 + cg + 8] = *(const uint4*)&o[8];
      }
    }
    __syncthreads();
  }
}

// ---------------------------------------------------------------------------
// MFMA GEMM, layers 2-4 (round 7/11, proven): out = bf16((X@W)*snorm).
// ---------------------------------------------------------------------------
__global__ __launch_bounds__(256) void gemm_mfma_kernel(
    const unsigned short* __restrict__ X, const unsigned short* __restrict__ WT,
    const float* __restrict__ norm, unsigned short* __restrict__ out, int n) {
  __shared__ float ol[64][68];
  const int t = threadIdx.x;
  const int l = t & 63;
  const int w = t >> 6;
  const int node0 = blockIdx.x * 64;
  const int row = l & 15, kg = l >> 4;

  int arow = node0 + w * 16 + row;
  if (arow > n - 1) arow = n - 1;
  const unsigned short* ab = X + (size_t)arow * 64 + kg * 8;
  bf16x8 a0 = *(const bf16x8*)(ab);
  bf16x8 a1 = *(const bf16x8*)(ab + 32);

  f32x4 acc[4];
#pragma unroll
  for (int ct = 0; ct < 4; ct++) acc[ct] = (f32x4){0.f, 0.f, 0.f, 0.f};

#pragma unroll
  for (int ct = 0; ct < 4; ct++) {
    const unsigned short* wb = WT + (size_t)(ct * 16 + row) * 64 + kg * 8;
    bf16x8 b0 = *(const bf16x8*)(wb);
    bf16x8 b1 = *(const bf16x8*)(wb + 32);
    acc[ct] = __builtin_amdgcn_mfma_f32_16x16x32_bf16(a0, b0, acc[ct], 0, 0, 0);
    acc[ct] = __builtin_amdgcn_mfma_f32_16x16x32_bf16(a1, b1, acc[ct], 0, 0, 0);
  }

#pragma unroll
  for (int ct = 0; ct < 4; ct++)
#pragma unroll
    for (int i = 0; i < 4; i++)
      ol[w * 16 + kg * 4 + i][ct * 16 + row] = acc[ct][i];
  __syncthreads();

  {
    int r2 = t >> 2, cg = (t & 3) * 16;
    int node = node0 + r2;
    if (node < n) {
      float s = norm[node];
      unsigned short o[16];
#pragma unroll
      for (int i = 0; i < 16; i++) o[i] = f2bf(ol[r2][cg + i] * s);
      *(uint4*)&out[(size_t)node * 64 + cg] = *(const uint4*)&o[0];
      *(uint4*)&out[(size_t)node * 64 + cg + 8] = *(const uint4*)&o[8];
    }
  }
}

// ---------------------------------------------------------------------------
// Aggregate (round 6/11, proven): node PAIR per wave. lane = (sub, fl):
// sub = lane>>4 edge-in-slot, fl = lane&15 feature quad (uint2 = 4 bf16).
// ---------------------------------------------------------------------------
template <int RELU>
__global__ __launch_bounds__(256) void agg_kernel(
    const unsigned short* __restrict__ H, const int* __restrict__ cnt_arr,
    const int* __restrict__ col, const float* __restrict__ dnorm,
    const float* __restrict__ bias, unsigned short* __restrict__ O,
    int n) {
  const int lane = threadIdx.x & 63;
  const int sub = lane >> 4;
  const int fl  = lane & 15;
  const int wave = (blockIdx.x * blockDim.x + threadIdx.x) >> 6;
  const int nwaves = (gridDim.x * blockDim.x) >> 6;
  const uint2* __restrict__ H2 = (const uint2*)H;
  const float4 bb = ((const float4*)bias)[fl];

  for (int v0 = wave * 2; v0 < n; v0 += nwaves * 2) {
    const int v1 = v0 + 1;
    int cnt0 = cnt_arr[v0];
    int cnt1 = (v1 < n) ? cnt_arr[v1] : 0;
    if (cnt0 > SLOTS) cnt0 = SLOTS;
    if (cnt1 > SLOTS) cnt1 = SLOTS;
    const size_t base0 = (size_t)v0 * SLOTS;
    const size_t base1 = (size_t)v1 * SLOTS;
    int cv0 = (lane < cnt0) ? col[base0 + lane] : 0;
    int cv1 = (lane < cnt1) ? col[base1 + lane] : 0;
    float a0[4] = {0.f, 0.f, 0.f, 0.f};
    float b0[4] = {0.f, 0.f, 0.f, 0.f};
    float a1[4] = {0.f, 0.f, 0.f, 0.f};
    float b1[4] = {0.f, 0.f, 0.f, 0.f};
    const int cmax = cnt0 > cnt1 ? cnt0 : cnt1;
    for (int j = 0; j < cmax; j += 8) {
      const int e0 = j + sub;
      const int e1 = j + 4 + sub;
      int c00 = __shfl(cv0, e0);
      int c01 = __shfl(cv0, e1);
      int c10 = __shfl(cv1, e0);
      int c11 = __shfl(cv1, e1);
      if (e0 < cnt0) { uint2 u = H2[(size_t)c00 * 16 + fl]; UNPACK_ADD(u, a0) }
      if (e0 < cnt1) { uint2 u = H2[(size_t)c10 * 16 + fl]; UNPACK_ADD(u, a1) }
      if (e1 < cnt0) { uint2 u = H2[(size_t)c01 * 16 + fl]; UNPACK_ADD(u, b0) }
      if (e1 < cnt1) { uint2 u = H2[(size_t)c11 * 16 + fl]; UNPACK_ADD(u, b1) }
    }
    float r0[4], r1[4];
#pragma unroll
    for (int i = 0; i < 4; i++) {
      float s0 = a0[i] + b0[i];
      s0 += __shfl_xor(s0, 16);
      s0 += __shfl_xor(s0, 32);
      r0[i] = s0;
      float s1 = a1[i] + b1[i];
      s1 += __shfl_xor(s1, 16);
      s1 += __shfl_xor(s1, 32);
      r1[i] = s1;
    }
    if (sub == 0) {
      float d = dnorm[v0];
      float q0 = r0[0] * d + bb.x;
      float q1 = r0[1] * d + bb.y;
      float q2 = r0[2] * d + bb.z;
      float q3 = r0[3] * d + bb.w;
      if (RELU) {
        q0 = fmaxf(q0, 0.f); q1 = fmaxf(q1, 0.f);
        q2 = fmaxf(q2, 0.f); q3 = fmaxf(q3, 0.f);
      }
      ushort4 o;
      o.x = f2bf(q0); o.y = f2bf(q1); o.z = f2bf(q2); o.w = f2bf(q3);
      *(ushort4*)&O[base0 + 4 * fl] = o;
    } else if (sub == 1 && v1 < n) {
      float d = dnorm[v1];
      float q0 = r1[0] * d + bb.x;
      float q1 = r1[1] * d + bb.y;
      float q2 = r1[2] * d + bb.z;
      float q3 = r1[3] * d + bb.w;
      if (RELU) {
        q0 = fmaxf(q0, 0.f); q1 = fmaxf(q1, 0.f);
        q2 = fmaxf(q2, 0.f); q3 = fmaxf(q3, 0.f);
      }
      ushort4 o;
      o.x = f2bf(q0); o.y = f2bf(q1); o.z = f2bf(q2); o.w = f2bf(q3);
      *(ushort4*)&O[base1 + 4 * fl] = o;
    }
  }
}

// ---------------------------------------------------------------------------
// Final: out[n][16] = relu(O4 + R) @ Wop + bop  (O4, R bf16)
// ---------------------------------------------------------------------------
__global__ __launch_bounds__(256) void final_kernel(
    const unsigned short* __restrict__ O4, const unsigned short* __restrict__ R,
    const float* __restrict__ Wop, const float* __restrict__ bop,
    float* __restrict__ out, int n) {
  __shared__ float t_lds[64][68];
  __shared__ float wop_lds[64][16];
  const int t = threadIdx.x;
  const int node0 = blockIdx.x * 64;
  const int srow = t >> 2;
  const int scol = (t & 3) * 16;

  ((float4*)&wop_lds[0][0])[t] = ((const float4*)Wop)[t];

  {
    int gi = node0 + srow;
    float f[16];
    if (gi < n) {
      const unsigned short* po = O4 + (size_t)gi * 64 + scol;
      const unsigned short* pr = R + (size_t)gi * 64 + scol;
      uint4 uo0 = *(const uint4*)(po + 0);
      uint4 uo1 = *(const uint4*)(po + 8);
      uint4 ur0 = *(const uint4*)(pr + 0);
      uint4 ur1 = *(const uint4*)(pr + 8);
      float o0, o1, rr0, rr1;
#define ADDRELU2(UO, UR, idx)                         \
      bf2x2(UO, &o0, &o1); bf2x2(UR, &rr0, &rr1);     \
      f[idx] = fmaxf(o0 + rr0, 0.f);                  \
      f[idx + 1] = fmaxf(o1 + rr1, 0.f);
      ADDRELU2(uo0.x, ur0.x, 0)  ADDRELU2(uo0.y, ur0.y, 2)
      ADDRELU2(uo0.z, ur0.z, 4)  ADDRELU2(uo0.w, ur0.w, 6)
      ADDRELU2(uo1.x, ur1.x, 8)  ADDRELU2(uo1.y, ur1.y, 10)
      ADDRELU2(uo1.z, ur1.z, 12) ADDRELU2(uo1.w, ur1.w, 14)
#undef ADDRELU2
    } else {
#pragma unroll
      for (int j = 0; j < 16; j++) f[j] = 0.f;
    }
#pragma unroll
    for (int j = 0; j < 16; j += 4)
      *(float4*)&t_lds[srow][scol + j] = make_float4(f[j], f[j+1], f[j+2], f[j+3]);
  }
  __syncthreads();

  {
    int nn = t >> 2;
    int fg = t & 3;
    float4 a = ((const float4*)bop)[fg];
#pragma unroll 16
    for (int k = 0; k < 64; k++) {
      float tv = t_lds[nn][k];
      float4 w = *(const float4*)&wop_lds[k][fg * 4];
      a.x = fmaf(tv, w.x, a.x);
      a.y = fmaf(tv, w.y, a.y);
      a.z = fmaf(tv, w.z, a.z);
      a.w = fmaf(tv, w.w, a.w);
    }
    int node = node0 + nn;
    if (node < n) *(float4*)&out[(size_t)node * 16 + fg * 4] = a;
  }
}

extern "C" void kernel_launch(void* const* d_in, const int* in_sizes, int n_in,
                              void* d_out, int out_size, void* d_ws, size_t ws_size,
                              hipStream_t stream) {
  const float* x    = (const float*)d_in[0];
  const int*   src  = (const int*)d_in[1];
  const int*   dst  = (const int*)d_in[2];
  const float* W1   = (const float*)d_in[3];
  const float* b1   = (const float*)d_in[4];
  const float* W2   = (const float*)d_in[5];
  const float* b2   = (const float*)d_in[6];
  const float* W3   = (const float*)d_in[7];
  const float* b3   = (const float*)d_in[8];
  const float* W4   = (const float*)d_in[9];
  const float* b4   = (const float*)d_in[10];
  const float* Wres = (const float*)d_in[11];
  const float* bres = (const float*)d_in[12];
  const float* Wop  = (const float*)d_in[13];
  const float* bop  = (const float*)d_in[14];
  float* out = (float*)d_out;

  const int N = in_sizes[0] / 128;
  const int E = in_sizes[1];
  const int nbuck = (N + 255) >> 8;

  char* p = (char*)d_ws;
  auto alloc = [&](size_t b) {
    char* r = p;
    p += (b + 255) & ~(size_t)255;
    return r;
  };
  int*            gcur_d  = (int*)alloc((size_t)nbuck * 4);
  int*            gcur_s  = (int*)alloc((size_t)nbuck * 4);
  unsigned short* WT      = (unsigned short*)alloc(28672 * 2);
  unsigned*       dbuck   = (unsigned*)alloc((size_t)nbuck * BCAP * 4);
  unsigned char*  sbuck   = (unsigned char*)alloc((size_t)nbuck * BCAP);
  int*            col     = (int*)alloc((size_t)N * SLOTS * 4);
  int*            cnt_arr = (int*)alloc((size_t)N * 4);
  float*          snorm   = (float*)alloc((size_t)N * 4);
  float*          dnorm   = (float*)alloc((size_t)N * 4);
  unsigned short* Hbuf    = (unsigned short*)alloc((size_t)N * 64 * 2);
  unsigned short* Obuf    = (unsigned short*)alloc((size_t)N * 64 * 2);
  unsigned short* Rbuf    = (unsigned short*)alloc((size_t)N * 64 * 2);

  unsigned short* W1T   = WT;
  unsigned short* W2T   = WT + 8192;
  unsigned short* W3T   = WT + 12288;
  unsigned short* W4T   = WT + 16384;
  unsigned short* WresT = WT + 20480;

  prep_kernel<<<112, 256, 0, stream>>>(W1, W2, W3, W4, Wres, WT, gcur_d, gcur_s, nbuck);

  int ga = (E + ACHUNK - 1) / ACHUNK;
  bucket_kernel<<<ga, 256, 0, stream>>>(src, dst, gcur_d, gcur_s, dbuck, sbuck, E, nbuck);
  csrdeg_kernel<<<nbuck, 256, 0, stream>>>(dbuck, gcur_d, sbuck, gcur_s,
                                           col, cnt_arr, dnorm, snorm, N);

  int gb  = (N + 63) / 64;
  int gb1 = (N + 127) / 128;
  // Layer 1: H = (x@W1)*snorm ; R = x@Wres + bres
  gemm1_mfma_kernel<<<gb1, 256, 0, stream>>>(x, W1T, WresT, bres, snorm, Hbuf, Rbuf, N);
  agg_kernel<1><<<2048, 256, 0, stream>>>(Hbuf, cnt_arr, col, dnorm, b1, Obuf, N);
  // Layer 2
  gemm_mfma_kernel<<<gb, 256, 0, stream>>>(Obuf, W2T, snorm, Hbuf, N);
  agg_kernel<1><<<2048, 256, 0, stream>>>(Hbuf, cnt_arr, col, dnorm, b2, Obuf, N);
  // Layer 3
  gemm_mfma_kernel<<<gb, 256, 0, stream>>>(Obuf, W3T, snorm, Hbuf, N);
  agg_kernel<1><<<2048, 256, 0, stream>>>(Hbuf, cnt_arr, col, dnorm, b3, Obuf, N);
  // Layer 4 (no relu)
  gemm_mfma_kernel<<<gb, 256, 0, stream>>>(Obuf, W4T, snorm, Hbuf, N);
  agg_kernel<0><<<2048, 256, 0, stream>>>(Hbuf, cnt_arr, col, dnorm, b4, Obuf, N);
  // Final: relu(O4 + R) @ Wop + bop
  final_kernel<<<gb, 256, 0, stream>>>(Obuf, Rbuf, Wop, bop, out, N);
}

// Round 15
// 293.241 us; speedup vs baseline: 1.0819x; 1.0819x over previous
//
#include <hip/hip_runtime.h>
#include <cstdint>
#include <cstddef>

// ---------------------------------------------------------------------------
// GCN 4-layer + residual + FC on MI355X, round 15.
// - bucket_kernel: round-13 structure (LDS staging, ACHUNK 4096) but 512
//   threads/block -> 2x resident waves (grid was wave-limited, not LDS).
// - csrdeg_kernel: 512 threads (same reason).
// - Everything else: round-13 exact (298us best).
// ---------------------------------------------------------------------------

#define SLOTS 64
#define BCAP 5120
#define ACHUNK 4096
#define BTH 512

typedef __attribute__((ext_vector_type(8))) short bf16x8;
typedef __attribute__((ext_vector_type(4))) float f32x4;

__device__ __forceinline__ unsigned short f2bf(float f) {
  union { float f; unsigned u; } v; v.f = f;
  unsigned r = (v.u + 0x7fffu + ((v.u >> 16) & 1u)) >> 16;
  return (unsigned short)r;
}
__device__ __forceinline__ void bf2x2(unsigned u, float* lo, float* hi) {
  union { unsigned x; float f; } a, b;
  a.x = u << 16; b.x = u & 0xFFFF0000u;
  *lo = a.f; *hi = b.f;
}
__device__ __forceinline__ bf16x8 cvt8(float4 f0, float4 f1) {
  bf16x8 v;
  v[0] = (short)f2bf(f0.x); v[1] = (short)f2bf(f0.y);
  v[2] = (short)f2bf(f0.z); v[3] = (short)f2bf(f0.w);
  v[4] = (short)f2bf(f1.x); v[5] = (short)f2bf(f1.y);
  v[6] = (short)f2bf(f1.z); v[7] = (short)f2bf(f1.w);
  return v;
}

#define UNPACK_ADD(u, A)                         \
  { float f0_, f1_, f2_, f3_;                    \
    bf2x2((u).x, &f0_, &f1_);                    \
    bf2x2((u).y, &f2_, &f3_);                    \
    A[0] += f0_; A[1] += f1_; A[2] += f2_; A[3] += f3_; }

// ---------------------------------------------------------------------------
// prep: zero bucket cursors + build bf16 W^T for all weight matrices.
// ---------------------------------------------------------------------------
__global__ void prep_kernel(const float* __restrict__ W1, const float* __restrict__ W2,
                            const float* __restrict__ W3, const float* __restrict__ W4,
                            const float* __restrict__ Wres,
                            unsigned short* __restrict__ WT,
                            int* __restrict__ gcur_d, int* __restrict__ gcur_s, int nbuck) {
  int i = blockIdx.x * blockDim.x + threadIdx.x;
  if (i < nbuck) { gcur_d[i] = 0; gcur_s[i] = 0; }
  if (i < 8192) {
    int c = i >> 7, k = i & 127;
    WT[i] = f2bf(W1[k * 64 + c]);
  } else if (i < 12288) {
    int j = i - 8192; int c = j >> 6, k = j & 63;
    WT[i] = f2bf(W2[k * 64 + c]);
  } else if (i < 16384) {
    int j = i - 12288; int c = j >> 6, k = j & 63;
    WT[i] = f2bf(W3[k * 64 + c]);
  } else if (i < 20480) {
    int j = i - 16384; int c = j >> 6, k = j & 63;
    WT[i] = f2bf(W4[k * 64 + c]);
  } else if (i < 28672) {
    int j = i - 20480; int c = j >> 7, k = j & 127;
    WT[i] = f2bf(Wres[k * 64 + c]);
  }
}

// ---------------------------------------------------------------------------
// Pass A: bucket edges by dst>>8 (payload dl<<24|src) and src>>8 (byte).
// LDS-staged (round-13 pattern), 512 threads for 2x resident waves.
// ---------------------------------------------------------------------------
__global__ __launch_bounds__(BTH) void bucket_kernel(
    const int* __restrict__ src, const int* __restrict__ dst,
    int* __restrict__ gcur_d, int* __restrict__ gcur_s,
    unsigned* __restrict__ dbuck, unsigned char* __restrict__ sbuck,
    int E, int nbuck) {
  __shared__ int s_src[ACHUNK];
  __shared__ int s_dst[ACHUNK];
  __shared__ int run_d[512];
  __shared__ int run_s[512];
  const int t = threadIdx.x;
  const int base = blockIdx.x * ACHUNK;
  int cnt = E - base;
  if (cnt > ACHUNK) cnt = ACHUNK;

  for (int i = t; i < cnt; i += BTH) {
    s_src[i] = src[base + i];
    s_dst[i] = dst[base + i];
  }
  for (int i = t; i < 512; i += BTH) { run_d[i] = 0; run_s[i] = 0; }
  __syncthreads();
  for (int i = t; i < cnt; i += BTH) {
    atomicAdd(&run_d[s_dst[i] >> 8], 1);
    atomicAdd(&run_s[s_src[i] >> 8], 1);
  }
  __syncthreads();
  // Reserve global runs. UNIFORM trip count so barriers are non-divergent.
  {
    const int iters = (nbuck + BTH - 1) / BTH;
    for (int it = 0; it < iters; ++it) {
      int i = it * BTH + t;
      int hd = 0, hs = 0;
      if (i < nbuck) { hd = run_d[i]; hs = run_s[i]; }
      __syncthreads();
      if (i < nbuck) {
        run_d[i] = hd ? atomicAdd(&gcur_d[i], hd) : 0;
        run_s[i] = hs ? atomicAdd(&gcur_s[i], hs) : 0;
      }
      __syncthreads();
    }
  }
  for (int i = t; i < cnt; i += BTH) {
    int d = s_dst[i], s = s_src[i];
    int bd = d >> 8;
    int pd = atomicAdd(&run_d[bd], 1);
    if (pd < BCAP) dbuck[(size_t)bd * BCAP + pd] = ((unsigned)(d & 255) << 24) | (unsigned)s;
    int bs = s >> 8;
    int ps = atomicAdd(&run_s[bs], 1);
    if (ps < BCAP) sbuck[(size_t)bs * BCAP + ps] = (unsigned char)(s & 255);
  }
}

// ---------------------------------------------------------------------------
// Pass B (merged): per 256-node bucket -- dst scatter to col slots + cnt +
// dnorm, AND src histogram -> snorm. 512 threads.
// ---------------------------------------------------------------------------
__global__ __launch_bounds__(BTH) void csrdeg_kernel(
    const unsigned* __restrict__ dbuck, const int* __restrict__ gcur_d,
    const unsigned char* __restrict__ sbuck, const int* __restrict__ gcur_s,
    int* __restrict__ col, int* __restrict__ cnt_arr,
    float* __restrict__ dnorm, float* __restrict__ snorm, int N) {
  __shared__ int cur[256];
  __shared__ int curs[256];
  const int b = blockIdx.x;
  const int t = threadIdx.x;
  const int node0 = b << 8;
  if (t < 256) { cur[t] = 0; curs[t] = 0; }
  __syncthreads();
  int cntd = gcur_d[b];
  if (cntd > BCAP) cntd = BCAP;
  const unsigned* p = dbuck + (size_t)b * BCAP;
  for (int i = t; i < cntd; i += BTH) {
    unsigned e = p[i];
    int nl = e >> 24;
    int s = (int)(e & 0x00FFFFFFu);
    int pos = atomicAdd(&cur[nl], 1);
    if (pos < SLOTS) col[(size_t)(node0 + nl) * SLOTS + pos] = s;
  }
  int cnts = gcur_s[b];
  if (cnts > BCAP) cnts = BCAP;
  const unsigned char* ps = sbuck + (size_t)b * BCAP;
  for (int i = t; i < cnts; i += BTH) atomicAdd(&curs[ps[i]], 1);
  __syncthreads();
  if (t < 256) {
    int node = node0 + t;
    if (node < N) {
      int c = cur[t];
      cnt_arr[node] = c;
      dnorm[node] = rsqrtf((float)(c < 1 ? 1 : c));
      int cs = curs[t];
      snorm[node] = rsqrtf((float)(cs < 1 ? 1 : cs));
    }
  }
}

// ---------------------------------------------------------------------------
// MFMA GEMM layer 1 + residual: B-fragments fully hoisted to registers
// (static indices), 128 nodes per block (2 tiles), LDS epilogue.
// ---------------------------------------------------------------------------
__global__ __launch_bounds__(256, 2) void gemm1_mfma_kernel(
    const float* __restrict__ X, const unsigned short* __restrict__ W1T,
    const unsigned short* __restrict__ WresT, const float* __restrict__ bres,
    const float* __restrict__ norm,
    unsigned short* __restrict__ Hout, unsigned short* __restrict__ Rout, int n) {
  __shared__ float ol[64][68];
  const int t = threadIdx.x;
  const int l = t & 63;
  const int w = t >> 6;
  const int base0 = blockIdx.x * 128;
  const int cc16 = l & 15, kg = l >> 4;

  bf16x8 b1[4][4], br[4][4];
#pragma unroll
  for (int kh = 0; kh < 4; kh++) {
#pragma unroll
    for (int ct = 0; ct < 4; ct++) {
      b1[kh][ct] = *(const bf16x8*)(W1T + (size_t)(ct * 16 + cc16) * 128 + kh * 32 + kg * 8);
      br[kh][ct] = *(const bf16x8*)(WresT + (size_t)(ct * 16 + cc16) * 128 + kh * 32 + kg * 8);
    }
  }

  for (int q = 0; q < 2; q++) {
    const int node0 = base0 + q * 64;
    if (node0 >= n) break;

    int arow = node0 + w * 16 + cc16;
    if (arow > n - 1) arow = n - 1;
    const float* ap = X + (size_t)arow * 128 + kg * 8;
    bf16x8 a[4];
#pragma unroll
    for (int kh = 0; kh < 4; kh++) {
      float4 f0 = *(const float4*)(ap + kh * 32);
      float4 f1 = *(const float4*)(ap + kh * 32 + 4);
      a[kh] = cvt8(f0, f1);
    }

    f32x4 acc[4], acc2[4];
#pragma unroll
    for (int ct = 0; ct < 4; ct++) {
      acc[ct] = (f32x4){0.f, 0.f, 0.f, 0.f};
      acc2[ct] = (f32x4){0.f, 0.f, 0.f, 0.f};
    }
#pragma unroll
    for (int kh = 0; kh < 4; kh++) {
#pragma unroll
      for (int ct = 0; ct < 4; ct++) {
        acc[ct] = __builtin_amdgcn_mfma_f32_16x16x32_bf16(a[kh], b1[kh][ct], acc[ct], 0, 0, 0);
        acc2[ct] = __builtin_amdgcn_mfma_f32_16x16x32_bf16(a[kh], br[kh][ct], acc2[ct], 0, 0, 0);
      }
    }

    // H epilogue
#pragma unroll
    for (int ct = 0; ct < 4; ct++)
#pragma unroll
      for (int i = 0; i < 4; i++)
        ol[w * 16 + kg * 4 + i][ct * 16 + cc16] = acc[ct][i];
    __syncthreads();
    {
      int r2 = t >> 2, cg = (t & 3) * 16;
      int node = node0 + r2;
      if (node < n) {
        float s = norm[node];
        unsigned short o[16];
#pragma unroll
        for (int i = 0; i < 16; i++) o[i] = f2bf(ol[r2][cg + i] * s);
        *(uint4*)&Hout[(size_t)node * 64 + cg] = *(const uint4*)&o[0];
        *(uint4*)&Hout[(size_t)node * 64 + cg + 8] = *(const uint4*)&o[8];
      }
    }
    __syncthreads();

    // R epilogue
#pragma unroll
    for (int ct = 0; ct < 4; ct++)
#pragma unroll
      for (int i = 0; i < 4; i++)
        ol[w * 16 + kg * 4 + i][ct * 16 + cc16] = acc2[ct][i];
    __syncthreads();
    {
      int r2 = t >> 2, cg = (t & 3) * 16;
      int node = node0 + r2;
      if (node < n) {
        unsigned short o[16];
#pragma unroll
        for (int i = 0; i < 16; i++) o[i] = f2bf(ol[r2][cg + i] + bres[cg + i]);
        *(uint4*)&Rout[(size_t)node * 64 + cg] = *(const uint4*)&o[0];
        *(uint4*)&Rout[(size_t)node * 64 + cg + 8] = *(const uint4*)&o[8];
      }
    }
    __syncthreads();
  }
}

// ---------------------------------------------------------------------------
// MFMA GEMM, layers 2-4 (round 7/11, proven): out = bf16((X@W)*snorm).
// ---------------------------------------------------------------------------
__global__ __launch_bounds__(256) void gemm_mfma_kernel(
    const unsigned short* __restrict__ X, const unsigned short* __restrict__ WT,
    const float* __restrict__ norm, unsigned short* __restrict__ out, int n) {
  __shared__ float ol[64][68];
  const int t = threadIdx.x;
  const int l = t & 63;
  const int w = t >> 6;
  const int node0 = blockIdx.x * 64;
  const int row = l & 15, kg = l >> 4;

  int arow = node0 + w * 16 + row;
  if (arow > n - 1) arow = n - 1;
  const unsigned short* ab = X + (size_t)arow * 64 + kg * 8;
  bf16x8 a0 = *(const bf16x8*)(ab);
  bf16x8 a1 = *(const bf16x8*)(ab + 32);

  f32x4 acc[4];
#pragma unroll
  for (int ct = 0; ct < 4; ct++) acc[ct] = (f32x4){0.f, 0.f, 0.f, 0.f};

#pragma unroll
  for (int ct = 0; ct < 4; ct++) {
    const unsigned short* wb = WT + (size_t)(ct * 16 + row) * 64 + kg * 8;
    bf16x8 b0 = *(const bf16x8*)(wb);
    bf16x8 b1 = *(const bf16x8*)(wb + 32);
    acc[ct] = __builtin_amdgcn_mfma_f32_16x16x32_bf16(a0, b0, acc[ct], 0, 0, 0);
    acc[ct] = __builtin_amdgcn_mfma_f32_16x16x32_bf16(a1, b1, acc[ct], 0, 0, 0);
  }

#pragma unroll
  for (int ct = 0; ct < 4; ct++)
#pragma unroll
    for (int i = 0; i < 4; i++)
      ol[w * 16 + kg * 4 + i][ct * 16 + row] = acc[ct][i];
  __syncthreads();

  {
    int r2 = t >> 2, cg = (t & 3) * 16;
    int node = node0 + r2;
    if (node < n) {
      float s = norm[node];
      unsigned short o[16];
#pragma unroll
      for (int i = 0; i < 16; i++) o[i] = f2bf(ol[r2][cg + i] * s);
      *(uint4*)&out[(size_t)node * 64 + cg] = *(const uint4*)&o[0];
      *(uint4*)&out[(size_t)node * 64 + cg + 8] = *(const uint4*)&o[8];
    }
  }
}

// ---------------------------------------------------------------------------
// Aggregate (round 6/11, proven): node PAIR per wave. lane = (sub, fl):
// sub = lane>>4 edge-in-slot, fl = lane&15 feature quad (uint2 = 4 bf16).
// ---------------------------------------------------------------------------
template <int RELU>
__global__ __launch_bounds__(256) void agg_kernel(
    const unsigned short* __restrict__ H, const int* __restrict__ cnt_arr,
    const int* __restrict__ col, const float* __restrict__ dnorm,
    const float* __restrict__ bias, unsigned short* __restrict__ O,
    int n) {
  const int lane = threadIdx.x & 63;
  const int sub = lane >> 4;
  const int fl  = lane & 15;
  const int wave = (blockIdx.x * blockDim.x + threadIdx.x) >> 6;
  const int nwaves = (gridDim.x * blockDim.x) >> 6;
  const uint2* __restrict__ H2 = (const uint2*)H;
  const float4 bb = ((const float4*)bias)[fl];

  for (int v0 = wave * 2; v0 < n; v0 += nwaves * 2) {
    const int v1 = v0 + 1;
    int cnt0 = cnt_arr[v0];
    int cnt1 = (v1 < n) ? cnt_arr[v1] : 0;
    if (cnt0 > SLOTS) cnt0 = SLOTS;
    if (cnt1 > SLOTS) cnt1 = SLOTS;
    const size_t base0 = (size_t)v0 * SLOTS;
    const size_t base1 = (size_t)v1 * SLOTS;
    int cv0 = (lane < cnt0) ? col[base0 + lane] : 0;
    int cv1 = (lane < cnt1) ? col[base1 + lane] : 0;
    float a0[4] = {0.f, 0.f, 0.f, 0.f};
    float b0[4] = {0.f, 0.f, 0.f, 0.f};
    float a1[4] = {0.f, 0.f, 0.f, 0.f};
    float b1[4] = {0.f, 0.f, 0.f, 0.f};
    const int cmax = cnt0 > cnt1 ? cnt0 : cnt1;
    for (int j = 0; j < cmax; j += 8) {
      const int e0 = j + sub;
      const int e1 = j + 4 + sub;
      int c00 = __shfl(cv0, e0);
      int c01 = __shfl(cv0, e1);
      int c10 = __shfl(cv1, e0);
      int c11 = __shfl(cv1, e1);
      if (e0 < cnt0) { uint2 u = H2[(size_t)c00 * 16 + fl]; UNPACK_ADD(u, a0) }
      if (e0 < cnt1) { uint2 u = H2[(size_t)c10 * 16 + fl]; UNPACK_ADD(u, a1) }
      if (e1 < cnt0) { uint2 u = H2[(size_t)c01 * 16 + fl]; UNPACK_ADD(u, b0) }
      if (e1 < cnt1) { uint2 u = H2[(size_t)c11 * 16 + fl]; UNPACK_ADD(u, b1) }
    }
    float r0[4], r1[4];
#pragma unroll
    for (int i = 0; i < 4; i++) {
      float s0 = a0[i] + b0[i];
      s0 += __shfl_xor(s0, 16);
      s0 += __shfl_xor(s0, 32);
      r0[i] = s0;
      float s1 = a1[i] + b1[i];
      s1 += __shfl_xor(s1, 16);
      s1 += __shfl_xor(s1, 32);
      r1[i] = s1;
    }
    if (sub == 0) {
      float d = dnorm[v0];
      float q0 = r0[0] * d + bb.x;
      float q1 = r0[1] * d + bb.y;
      float q2 = r0[2] * d + bb.z;
      float q3 = r0[3] * d + bb.w;
      if (RELU) {
        q0 = fmaxf(q0, 0.f); q1 = fmaxf(q1, 0.f);
        q2 = fmaxf(q2, 0.f); q3 = fmaxf(q3, 0.f);
      }
      ushort4 o;
      o.x = f2bf(q0); o.y = f2bf(q1); o.z = f2bf(q2); o.w = f2bf(q3);
      *(ushort4*)&O[base0 + 4 * fl] = o;
    } else if (sub == 1 && v1 < n) {
      float d = dnorm[v1];
      float q0 = r1[0] * d + bb.x;
      float q1 = r1[1] * d + bb.y;
      float q2 = r1[2] * d + bb.z;
      float q3 = r1[3] * d + bb.w;
      if (RELU) {
        q0 = fmaxf(q0, 0.f); q1 = fmaxf(q1, 0.f);
        q2 = fmaxf(q2, 0.f); q3 = fmaxf(q3, 0.f);
      }
      ushort4 o;
      o.x = f2bf(q0); o.y = f2bf(q1); o.z = f2bf(q2); o.w = f2bf(q3);
      *(ushort4*)&O[base1 + 4 * fl] = o;
    }
  }
}

// ---------------------------------------------------------------------------
// Final: out[n][16] = relu(O4 + R) @ Wop + bop  (O4, R bf16)
// ---------------------------------------------------------------------------
__global__ __launch_bounds__(256) void final_kernel(
    const unsigned short* __restrict__ O4, const unsigned short* __restrict__ R,
    const float* __restrict__ Wop, const float* __restrict__ bop,
    float* __restrict__ out, int n) {
  __shared__ float t_lds[64][68];
  __shared__ float wop_lds[64][16];
  const int t = threadIdx.x;
  const int node0 = blockIdx.x * 64;
  const int srow = t >> 2;
  const int scol = (t & 3) * 16;

  ((float4*)&wop_lds[0][0])[t] = ((const float4*)Wop)[t];

  {
    int gi = node0 + srow;
    float f[16];
    if (gi < n) {
      const unsigned short* po = O4 + (size_t)gi * 64 + scol;
      const unsigned short* pr = R + (size_t)gi * 64 + scol;
      uint4 uo0 = *(const uint4*)(po + 0);
      uint4 uo1 = *(const uint4*)(po + 8);
      uint4 ur0 = *(const uint4*)(pr + 0);
      uint4 ur1 = *(const uint4*)(pr + 8);
      float o0, o1, rr0, rr1;
#define ADDRELU2(UO, UR, idx)                         \
      bf2x2(UO, &o0, &o1); bf2x2(UR, &rr0, &rr1);     \
      f[idx] = fmaxf(o0 + rr0, 0.f);                  \
      f[idx + 1] = fmaxf(o1 + rr1, 0.f);
      ADDRELU2(uo0.x, ur0.x, 0)  ADDRELU2(uo0.y, ur0.y, 2)
      ADDRELU2(uo0.z, ur0.z, 4)  ADDRELU2(uo0.w, ur0.w, 6)
      ADDRELU2(uo1.x, ur1.x, 8)  ADDRELU2(uo1.y, ur1.y, 10)
      ADDRELU2(uo1.z, ur1.z, 12) ADDRELU2(uo1.w, ur1.w, 14)
#undef ADDRELU2
    } else {
#pragma unroll
      for (int j = 0; j < 16; j++) f[j] = 0.f;
    }
#pragma unroll
    for (int j = 0; j < 16; j += 4)
      *(float4*)&t_lds[srow][scol + j] = make_float4(f[j], f[j+1], f[j+2], f[j+3]);
  }
  __syncthreads();

  {
    int nn = t >> 2;
    int fg = t & 3;
    float4 a = ((const float4*)bop)[fg];
#pragma unroll 16
    for (int k = 0; k < 64; k++) {
      float tv = t_lds[nn][k];
      float4 w = *(const float4*)&wop_lds[k][fg * 4];
      a.x = fmaf(tv, w.x, a.x);
      a.y = fmaf(tv, w.y, a.y);
      a.z = fmaf(tv, w.z, a.z);
      a.w = fmaf(tv, w.w, a.w);
    }
    int node = node0 + nn;
    if (node < n) *(float4*)&out[(size_t)node * 16 + fg * 4] = a;
  }
}

extern "C" void kernel_launch(void* const* d_in, const int* in_sizes, int n_in,
                              void* d_out, int out_size, void* d_ws, size_t ws_size,
                              hipStream_t stream) {
  const float* x    = (const float*)d_in[0];
  const int*   src  = (const int*)d_in[1];
  const int*   dst  = (const int*)d_in[2];
  const float* W1   = (const float*)d_in[3];
  const float* b1   = (const float*)d_in[4];
  const float* W2   = (const float*)d_in[5];
  const float* b2   = (const float*)d_in[6];
  const float* W3   = (const float*)d_in[7];
  const float* b3   = (const float*)d_in[8];
  const float* W4   = (const float*)d_in[9];
  const float* b4   = (const float*)d_in[10];
  const float* Wres = (const float*)d_in[11];
  const float* bres = (const float*)d_in[12];
  const float* Wop  = (const float*)d_in[13];
  const float* bop  = (const float*)d_in[14];
  float* out = (float*)d_out;

  const int N = in_sizes[0] / 128;
  const int E = in_sizes[1];
  const int nbuck = (N + 255) >> 8;

  char* p = (char*)d_ws;
  auto alloc = [&](size_t b) {
    char* r = p;
    p += (b + 255) & ~(size_t)255;
    return r;
  };
  int*            gcur_d  = (int*)alloc((size_t)nbuck * 4);
  int*            gcur_s  = (int*)alloc((size_t)nbuck * 4);
  unsigned short* WT      = (unsigned short*)alloc(28672 * 2);
  unsigned*       dbuck   = (unsigned*)alloc((size_t)nbuck * BCAP * 4);
  unsigned char*  sbuck   = (unsigned char*)alloc((size_t)nbuck * BCAP);
  int*            col     = (int*)alloc((size_t)N * SLOTS * 4);
  int*            cnt_arr = (int*)alloc((size_t)N * 4);
  float*          snorm   = (float*)alloc((size_t)N * 4);
  float*          dnorm   = (float*)alloc((size_t)N * 4);
  unsigned short* Hbuf    = (unsigned short*)alloc((size_t)N * 64 * 2);
  unsigned short* Obuf    = (unsigned short*)alloc((size_t)N * 64 * 2);
  unsigned short* Rbuf    = (unsigned short*)alloc((size_t)N * 64 * 2);

  unsigned short* W1T   = WT;
  unsigned short* W2T   = WT + 8192;
  unsigned short* W3T   = WT + 12288;
  unsigned short* W4T   = WT + 16384;
  unsigned short* WresT = WT + 20480;

  prep_kernel<<<112, 256, 0, stream>>>(W1, W2, W3, W4, Wres, WT, gcur_d, gcur_s, nbuck);

  int ga = (E + ACHUNK - 1) / ACHUNK;
  bucket_kernel<<<ga, BTH, 0, stream>>>(src, dst, gcur_d, gcur_s, dbuck, sbuck, E, nbuck);
  csrdeg_kernel<<<nbuck, BTH, 0, stream>>>(dbuck, gcur_d, sbuck, gcur_s,
                                           col, cnt_arr, dnorm, snorm, N);

  int gb  = (N + 63) / 64;
  int gb1 = (N + 127) / 128;
  // Layer 1: H = (x@W1)*snorm ; R = x@Wres + bres
  gemm1_mfma_kernel<<<gb1, 256, 0, stream>>>(x, W1T, WresT, bres, snorm, Hbuf, Rbuf, N);
  agg_kernel<1><<<2048, 256, 0, stream>>>(Hbuf, cnt_arr, col, dnorm, b1, Obuf, N);
  // Layer 2
  gemm_mfma_kernel<<<gb, 256, 0, stream>>>(Obuf, W2T, snorm, Hbuf, N);
  agg_kernel<1><<<2048, 256, 0, stream>>>(Hbuf, cnt_arr, col, dnorm, b2, Obuf, N);
  // Layer 3
  gemm_mfma_kernel<<<gb, 256, 0, stream>>>(Obuf, W3T, snorm, Hbuf, N);
  agg_kernel<1><<<2048, 256, 0, stream>>>(Hbuf, cnt_arr, col, dnorm, b3, Obuf, N);
  // Layer 4 (no relu)
  gemm_mfma_kernel<<<gb, 256, 0, stream>>>(Obuf, W4T, snorm, Hbuf, N);
  agg_kernel<0><<<2048, 256, 0, stream>>>(Hbuf, cnt_arr, col, dnorm, b4, Obuf, N);
  // Final: relu(O4 + R) @ Wop + bop
  final_kernel<<<gb, 256, 0, stream>>>(Obuf, Rbuf, Wop, bop, out, N);
}